// Round 3
// baseline (336.983 us; speedup 1.0000x reference)
//
#include <hip/hip_runtime.h>

#define NNODES 50000
#define NEDGES 800000
#define DIM 96
#define LLDIM 64
#define NRELS 3            // metapath relations 0,1,2
#define SCAN_N (NRELS * NNODES)

// ---------------- CSR build ----------------

__global__ void hist_kernel(const int* __restrict__ ei, const int* __restrict__ et,
                            int* __restrict__ deg) {
    int e = blockIdx.x * 256 + threadIdx.x;
    if (e >= NEDGES) return;
    int r = et[e];
    if (r < NRELS) atomicAdd(&deg[r * NNODES + ei[e]], 1);
}

__global__ void scan1_kernel(const int* __restrict__ in, int* __restrict__ out,
                             int* __restrict__ partials, int n) {
    __shared__ int sdata[256];
    int tid = threadIdx.x;
    int base = blockIdx.x * 1024 + tid * 4;
    int v0 = (base + 0 < n) ? in[base + 0] : 0;
    int v1 = (base + 1 < n) ? in[base + 1] : 0;
    int v2 = (base + 2 < n) ? in[base + 2] : 0;
    int v3 = (base + 3 < n) ? in[base + 3] : 0;
    int tsum = v0 + v1 + v2 + v3;
    sdata[tid] = tsum;
    __syncthreads();
    for (int off = 1; off < 256; off <<= 1) {
        int x = sdata[tid];
        int y = (tid >= off) ? sdata[tid - off] : 0;
        __syncthreads();
        sdata[tid] = x + y;
        __syncthreads();
    }
    int excl = sdata[tid] - tsum;
    if (tid == 255) partials[blockIdx.x] = sdata[255];
    if (base + 0 < n) out[base + 0] = excl;
    excl += v0;
    if (base + 1 < n) out[base + 1] = excl;
    excl += v1;
    if (base + 2 < n) out[base + 2] = excl;
    excl += v2;
    if (base + 3 < n) out[base + 3] = excl;
}

__global__ void scan2_kernel(int* __restrict__ partials, int nb) {
    __shared__ int sdata[256];
    int tid = threadIdx.x;
    int v = (tid < nb) ? partials[tid] : 0;
    sdata[tid] = v;
    __syncthreads();
    for (int off = 1; off < 256; off <<= 1) {
        int x = sdata[tid];
        int y = (tid >= off) ? sdata[tid - off] : 0;
        __syncthreads();
        sdata[tid] = x + y;
        __syncthreads();
    }
    partials[tid] = sdata[tid] - v;   // exclusive
}

__global__ void scan3_kernel(int* __restrict__ out, const int* __restrict__ partials, int n) {
    int idx = blockIdx.x * 256 + threadIdx.x;
    if (idx < n) out[idx] += partials[idx >> 10];
}

__global__ void fill_kernel(const int* __restrict__ ei, const int* __restrict__ et,
                            int* __restrict__ cursor, int* __restrict__ col) {
    int e = blockIdx.x * 256 + threadIdx.x;
    if (e >= NEDGES) return;
    int r = et[e];
    if (r < NRELS) {
        int pos = atomicAdd(&cursor[r * NNODES + ei[e]], 1);
        col[pos] = ei[NEDGES + e];
    }
}

// ---------------- fused layer: gather(mean) + agg@W + h@R + bias + relu ----------------
// Block: 64 nodes x 96 cols, 192 threads (3 waves).
// LDS: Alds[96][68] holds agg-tile transposed (pass 0), then h-tile transposed (pass 1).
// Thread map: nq=tid%16 (node quad), coct=tid/16 (col oct) -> 4x8 accs.
// Hot-loop LDS: A read [k][nq*4] 2-way (free), W read [k][coct*8] near-broadcast.

__global__ __launch_bounds__(192) void fused_layer_kernel(
    const float* __restrict__ h, const int* __restrict__ rs,
    const int* __restrict__ re, const int* __restrict__ col,
    const float* __restrict__ W, const float* __restrict__ R,
    const float* __restrict__ b, float* __restrict__ out) {
    __shared__ __align__(16) float Alds[96][68];
    __shared__ __align__(16) float Wlds[24][96];
    int tid = threadIdx.x;
    int n0 = blockIdx.x * 64;
    int lane = tid & 31;
    int g = tid >> 5;                  // 6 groups of 32 lanes

    // ---- gather phase: mean of neighbor rows -> Alds[k][node] (transposed) ----
    for (int n = g; n < 64; n += 6) {
        int node = n0 + n;
        int nc = (node < NNODES) ? node : (NNODES - 1);
        int s = rs[nc];
        int e = re[nc];
        float a0 = 0.0f, a1 = 0.0f, a2 = 0.0f;
        int i = s;
        for (; i + 1 < e; i += 2) {          // 2 neighbors in flight for ILP
            int d0 = col[i];
            int d1 = col[i + 1];
            const float* r0 = h + (size_t)d0 * DIM;
            const float* r1 = h + (size_t)d1 * DIM;
            float u0 = r0[lane], u1 = r0[lane + 32], u2 = r0[lane + 64];
            float v0 = r1[lane], v1 = r1[lane + 32], v2 = r1[lane + 64];
            a0 += u0 + v0; a1 += u1 + v1; a2 += u2 + v2;
        }
        if (i < e) {
            const float* r0 = h + (size_t)col[i] * DIM;
            a0 += r0[lane]; a1 += r0[lane + 32]; a2 += r0[lane + 64];
        }
        float scl = 1.0f / fmaxf((float)(e - s), 1.0f);
        Alds[lane][n]      = a0 * scl;     // 4-way bank conflict, 192 stores/block - minor
        Alds[lane + 32][n] = a1 * scl;
        Alds[lane + 64][n] = a2 * scl;
    }

    int nq = tid & 15;       // node quad: nodes nq*4..nq*4+3
    int coct = tid >> 4;     // col oct: cols coct*8..coct*8+7 (0..11)

    float acc[4][8];
#pragma unroll
    for (int j = 0; j < 4; ++j)
#pragma unroll
        for (int c = 0; c < 8; ++c) acc[j][c] = 0.0f;

    for (int pass = 0; pass < 2; ++pass) {
        const float* B = pass ? R : W;
        if (pass) {
            __syncthreads();   // pass-0 compute done; safe to overwrite Alds
            // re-stage h-tile transposed: 64 rows x 24 float4
            for (int idx = tid; idx < 64 * 24; idx += 192) {
                int row = idx & 63;
                int kq = idx >> 6;
                int rn = n0 + row;
                if (rn >= NNODES) rn = NNODES - 1;
                float4 v = *(const float4*)(h + (size_t)rn * DIM + kq * 4);
                Alds[kq * 4 + 0][row] = v.x;
                Alds[kq * 4 + 1][row] = v.y;
                Alds[kq * 4 + 2][row] = v.z;
                Alds[kq * 4 + 3][row] = v.w;
            }
        }
        for (int chunk = 0; chunk < 4; ++chunk) {
            __syncthreads();
            // stage W chunk [24][96]
            for (int idx = tid; idx < 576; idx += 192) {
                int kr = idx / 24;
                int cq = idx % 24;
                *(float4*)&Wlds[kr][cq * 4] =
                    *(const float4*)(B + (size_t)(chunk * 24 + kr) * DIM + cq * 4);
            }
            __syncthreads();
            int kbase = chunk * 24;
#pragma unroll 6
            for (int k = 0; k < 24; ++k) {
                float4 a4 = *(float4*)&Alds[kbase + k][nq * 4];
                float4 w0 = *(float4*)&Wlds[k][coct * 8];
                float4 w1 = *(float4*)&Wlds[k][coct * 8 + 4];
                float av[4] = {a4.x, a4.y, a4.z, a4.w};
                float wv[8] = {w0.x, w0.y, w0.z, w0.w, w1.x, w1.y, w1.z, w1.w};
#pragma unroll
                for (int j = 0; j < 4; ++j)
#pragma unroll
                    for (int c = 0; c < 8; ++c) acc[j][c] += av[j] * wv[c];
            }
        }
    }

    // epilogue: bias + relu + store
    float4 b0 = *(const float4*)(b + coct * 8);
    float4 b1 = *(const float4*)(b + coct * 8 + 4);
#pragma unroll
    for (int j = 0; j < 4; ++j) {
        int n = n0 + nq * 4 + j;
        if (n < NNODES) {
            float4 r0, r1;
            r0.x = fmaxf(acc[j][0] + b0.x, 0.0f);
            r0.y = fmaxf(acc[j][1] + b0.y, 0.0f);
            r0.z = fmaxf(acc[j][2] + b0.z, 0.0f);
            r0.w = fmaxf(acc[j][3] + b0.w, 0.0f);
            r1.x = fmaxf(acc[j][4] + b1.x, 0.0f);
            r1.y = fmaxf(acc[j][5] + b1.y, 0.0f);
            r1.z = fmaxf(acc[j][6] + b1.z, 0.0f);
            r1.w = fmaxf(acc[j][7] + b1.w, 0.0f);
            *(float4*)(out + (size_t)n * DIM + coct * 8)     = r0;
            *(float4*)(out + (size_t)n * DIM + coct * 8 + 4) = r1;
        }
    }
}

// ---------------- final linear: out = h @ lin_w + lin_b (no relu) ----------------

__global__ __launch_bounds__(256) void final_kernel(
    const float* __restrict__ h, const float* __restrict__ LW,
    const float* __restrict__ LB, float* __restrict__ out) {
    __shared__ __align__(16) float Alds[32][68];
    __shared__ __align__(16) float Wlds[32][LLDIM];
    int tid = threadIdx.x;
    int q = tid % 16;
    int nb = tid / 16;
    int n0 = blockIdx.x * 64;

    float acc[4][4];
#pragma unroll
    for (int j = 0; j < 4; ++j)
#pragma unroll
        for (int c = 0; c < 4; ++c) acc[j][c] = 0.0f;

    for (int chunk = 0; chunk < 3; ++chunk) {
        int kc = chunk * 32;
        __syncthreads();
        for (int idx = tid; idx < 512; idx += 256) {
            int row = idx >> 3;
            int kq = idx & 7;
            int rnode = n0 + row;
            if (rnode >= NNODES) rnode = NNODES - 1;
            float4 v = *(const float4*)(h + (size_t)rnode * DIM + kc + kq * 4);
            int kk = kq * 4;
            Alds[kk + 0][row] = v.x;
            Alds[kk + 1][row] = v.y;
            Alds[kk + 2][row] = v.z;
            Alds[kk + 3][row] = v.w;
        }
        for (int idx = tid; idx < 512; idx += 256) {
            int kr = idx / 16;
            int cq = idx % 16;
            *(float4*)&Wlds[kr][cq * 4] =
                *(const float4*)(LW + (size_t)(kc + kr) * LLDIM + cq * 4);
        }
        __syncthreads();
#pragma unroll 8
        for (int k = 0; k < 32; ++k) {
            float4 w4 = *(float4*)&Wlds[k][q * 4];
            float4 a4 = *(float4*)&Alds[k][nb * 4];
            acc[0][0] += a4.x * w4.x; acc[0][1] += a4.x * w4.y;
            acc[0][2] += a4.x * w4.z; acc[0][3] += a4.x * w4.w;
            acc[1][0] += a4.y * w4.x; acc[1][1] += a4.y * w4.y;
            acc[1][2] += a4.y * w4.z; acc[1][3] += a4.y * w4.w;
            acc[2][0] += a4.z * w4.x; acc[2][1] += a4.z * w4.y;
            acc[2][2] += a4.z * w4.z; acc[2][3] += a4.z * w4.w;
            acc[3][0] += a4.w * w4.x; acc[3][1] += a4.w * w4.y;
            acc[3][2] += a4.w * w4.z; acc[3][3] += a4.w * w4.w;
        }
    }

    float4 bv = *(const float4*)(LB + q * 4);
    int nbase = n0 + nb * 4;
#pragma unroll
    for (int j = 0; j < 4; ++j) {
        int n = nbase + j;
        if (n < NNODES) {
            float4 r;
            r.x = acc[j][0] + bv.x;
            r.y = acc[j][1] + bv.y;
            r.z = acc[j][2] + bv.z;
            r.w = acc[j][3] + bv.w;
            *(float4*)(out + (size_t)n * LLDIM + q * 4) = r;
        }
    }
}

extern "C" void kernel_launch(void* const* d_in, const int* in_sizes, int n_in,
                              void* d_out, int out_size, void* d_ws, size_t ws_size,
                              hipStream_t stream) {
    const float* x     = (const float*)d_in[0];
    const int*   ei    = (const int*)d_in[1];
    const int*   et    = (const int*)d_in[2];
    const float* w1    = (const float*)d_in[3];
    const float* root1 = (const float*)d_in[4];
    const float* b1    = (const float*)d_in[5];
    const float* w2    = (const float*)d_in[6];
    const float* root2 = (const float*)d_in[7];
    const float* b2    = (const float*)d_in[8];
    const float* lin_w = (const float*)d_in[9];
    const float* lin_b = (const float*)d_in[10];

    float* bufA = (float*)d_ws;                      // N*96
    float* bufB = bufA + (size_t)NNODES * DIM;       // N*96
    int* deg       = (int*)(bufB + (size_t)NNODES * DIM);
    int* row_start = deg + SCAN_N;
    int* row_end   = row_start + SCAN_N;
    int* col       = row_end + SCAN_N;               // up to NEDGES
    int* partials  = col + NEDGES;                   // 256

    const int edge_blocks = (NEDGES + 255) / 256;
    const int scan_blocks = (SCAN_N + 1023) / 1024;  // 147
    const int node_tiles  = (NNODES + 63) / 64;      // 782

    // ---- CSR build (edge structure identical for all 3 layers) ----
    hipMemsetAsync(deg, 0, SCAN_N * sizeof(int), stream);
    hist_kernel<<<edge_blocks, 256, 0, stream>>>(ei, et, deg);
    scan1_kernel<<<scan_blocks, 256, 0, stream>>>(deg, row_start, partials, SCAN_N);
    scan2_kernel<<<1, 256, 0, stream>>>(partials, scan_blocks);
    scan3_kernel<<<(SCAN_N + 255) / 256, 256, 0, stream>>>(row_start, partials, SCAN_N);
    hipMemcpyAsync(row_end, row_start, SCAN_N * sizeof(int), hipMemcpyDeviceToDevice, stream);
    fill_kernel<<<edge_blocks, 256, 0, stream>>>(ei, et, row_end, col);

    // ---- Layer 0: rel 0, w1[0], root1, b1 :  x -> bufA ----
    fused_layer_kernel<<<node_tiles, 192, 0, stream>>>(
        x, row_start + 0 * NNODES, row_end + 0 * NNODES, col, w1, root1, b1, bufA);

    // ---- Layer 1: rel 1, w2[1], root2, b2 :  bufA -> bufB ----
    fused_layer_kernel<<<node_tiles, 192, 0, stream>>>(
        bufA, row_start + 1 * NNODES, row_end + 1 * NNODES, col,
        w2 + (size_t)1 * DIM * DIM, root2, b2, bufB);

    // ---- Layer 2: rel 2, w2[2], root2, b2 :  bufB -> bufA ----
    fused_layer_kernel<<<node_tiles, 192, 0, stream>>>(
        bufB, row_start + 2 * NNODES, row_end + 2 * NNODES, col,
        w2 + (size_t)2 * DIM * DIM, root2, b2, bufA);

    // ---- Final linear: bufA -> d_out ----
    final_kernel<<<node_tiles, 256, 0, stream>>>(bufA, lin_w, lin_b, (float*)d_out);
}